// Round 5
// baseline (118.283 us; speedup 1.0000x reference)
//
#include <hip/hip_runtime.h>
#include <math.h>

#define B_  2
#define N_  2048
#define NT_ 8
#define DZ_ 16
#define H_  64
#define W_  64

#define NSPLIT 4
#define NCH (N_/NSPLIT)               // 512 n's per block

#define XGRID_SIZE (B_*NT_*H_*W_*3)   // 196608 floats
#define ZGRID_SIZE (B_*NT_*H_*W_*DZ_) // 1048576 floats
#define CUT 16.0f                     // exp2(-16) ~ 1.5e-5; dropped mass ~5e-4

// ---------------------------------------------------------------------------
// R5: scalar-pipe z loads + deeper pipeline + NSPLIT x4 for load balance.
//
// Key insight: within a wave the compacted z-row index n is IDENTICAL for all
// lanes -> readfirstlane makes it SSA-uniform -> the 16 contiguous float
// loads become s_load_dwordx16 on the scalar pipe (SGPR destination). This
// sidesteps R4's VGPR-pressure serialization (VGPR_Count=32 showed the
// compiler refused to keep 8 float4 vector loads in flight). z values then
// feed v_fmac as the (single allowed) SGPR operand.
//
// Block = (split s, b, t, i): n in [s*512, s*512+512) for one (b,t,i) row.
// phase 1: cull (dt*r0)^2+(di*r1)^2 < CUT, ballot-compact into LDS.
// phase 2: wave w: k = w+8m, 2 n's per iter; z rows + metadata prefetched
//          one iteration ahead in registers (unroll-2 ping-pong).
// phase 3: stride-17 LDS reduce, 4 global f32 atomics/thread into z_grid.
// ---------------------------------------------------------------------------
__global__ __launch_bounds__(256) void fused_kernel(
    const float* __restrict__ x,      // [B][N][3]
    const float* __restrict__ z,      // [B][N][16]
    const float* __restrict__ tg,     // [B][NT]
    const float* __restrict__ lsp,    // [3]
    float* __restrict__ out)          // x_grid (196608) ++ z_grid (1048576)
{
    const int rest = blockIdx.x & 1023;
    const int s    = blockIdx.x >> 10;   // n-split id 0..3
    const int i    = rest & 63;
    const int t    = (rest >> 6) & 7;
    const int b    = rest >> 9;
    const int tid  = threadIdx.x;
    const int w    = tid >> 6;     // wave id 0..3
    const int lane = tid & 63;
    const int j    = lane;         // lane = spatial j

    const float step = 2.0f / 63.0f;
    const float C    = 0.84932180f;   // sqrt(0.5 * log2(e))

    const float r0 = C / (1e-5f + log1pf(expf(lsp[0])));
    const float r1 = C / (1e-5f + log1pf(expf(lsp[1])));
    const float r2 = C / (1e-5f + log1pf(expf(lsp[2])));

    const float tval = tg[b*NT_ + t];
    const float gi   = -1.0f + step * (float)i;

    union SM {
        struct { float2 cuc[NCH + 24]; int cidx[NCH + 24]; } c;  // ~6.4 KB
        float red[4][64][DZ_ + 1];                               // 17408 B
    };
    __shared__ SM sm;
    __shared__ int s_cnt;

    if (tid == 0) s_cnt = 0;
    __syncthreads();

    // ---- phase 1: cull + compact this split's n-chunk ----
    const int nbase = s * NCH;
    const float* __restrict__ xb = x + (b*N_ + nbase)*3;
    for (int k0 = 0; k0 < NCH; k0 += 256) {
        int k = k0 + tid;
        float x0 = xb[k*3 + 0];
        float x1 = xb[k*3 + 1];
        float x2 = xb[k*3 + 2];
        float dt = (tval - x0) * r0;
        float di = (gi   - x1) * r1;
        float sq = dt*dt + di*di;
        bool keep = (sq < CUT);
        unsigned long long mb = __ballot(keep);
        int cnt = __popcll(mb);
        int base = 0;
        if (lane == 0) base = atomicAdd(&s_cnt, cnt);
        base = __shfl(base, 0, 64);
        if (keep) {
            int rank = __popcll(mb & ((1ull << lane) - 1ull));
            int pos  = base + rank;
            sm.c.cuc[pos]  = make_float2(exp2f(-sq), x2 * r2);
            sm.c.cidx[pos] = nbase + k;
        }
    }

    // x_grid row for this (b,t,i): written once (split 0 only), coalesced
    if (s == 0 && tid < 192) {
        int jj = tid / 3;
        int c  = tid - jj*3;
        float gj = -1.0f + step * (float)jj;
        float v  = (c == 0) ? tval : ((c == 1) ? gi : gj);
        out[(size_t)(((b*NT_ + t)*H_ + i)*W_)*3 + tid] = v;
    }

    __syncthreads();
    const int M = s_cnt;
    if (tid < 24) {                       // zero padding: guard-free inner loop
        sm.c.cuc[M + tid]  = make_float2(0.f, 0.f);
        sm.c.cidx[M + tid] = 0;
    }
    __syncthreads();

    // ---- phase 2: pipelined accumulate, z rows on the scalar pipe ----
    const float aj = (-1.0f + step * (float)j) * r2;
    const float* __restrict__ zb = z + b*N_*DZ_;

    float acc[DZ_];
    #pragma unroll
    for (int e = 0; e < DZ_; ++e) acc[e] = 0.0f;

    // prologue: metadata + z rows for first pair (padding makes this safe)
    float2 pA = sm.c.cuc[w];
    float2 pB = sm.c.cuc[w + 4];
    int nA = __builtin_amdgcn_readfirstlane(sm.c.cidx[w]);
    int nB = __builtin_amdgcn_readfirstlane(sm.c.cidx[w + 4]);
    float zAv[DZ_], zBv[DZ_];
    {
        const float* __restrict__ zA = zb + (size_t)nA * DZ_;
        const float* __restrict__ zB = zb + (size_t)nB * DZ_;
        #pragma unroll
        for (int e = 0; e < DZ_; ++e) zAv[e] = zA[e];
        #pragma unroll
        for (int e = 0; e < DZ_; ++e) zBv[e] = zB[e];
    }

    #pragma unroll 2
    for (int k = w; k < M; k += 8) {
        // prefetch next pair (meta via LDS broadcast, z via s_load_dwordx16)
        float2 pA2 = sm.c.cuc[k + 8];
        float2 pB2 = sm.c.cuc[k + 12];
        int nA2 = __builtin_amdgcn_readfirstlane(sm.c.cidx[k + 8]);
        int nB2 = __builtin_amdgcn_readfirstlane(sm.c.cidx[k + 12]);
        const float* __restrict__ zA2 = zb + (size_t)nA2 * DZ_;
        const float* __restrict__ zB2 = zb + (size_t)nB2 * DZ_;
        float zA2v[DZ_], zB2v[DZ_];
        #pragma unroll
        for (int e = 0; e < DZ_; ++e) zA2v[e] = zA2[e];
        #pragma unroll
        for (int e = 0; e < DZ_; ++e) zB2v[e] = zB2[e];

        // compute with current pair (z already resident in SGPRs)
        float dA = aj - pA.y;
        float dB = aj - pB.y;
        float wA = pA.x * exp2f(-(dA*dA));
        float wB = pB.x * exp2f(-(dB*dB));

        #pragma unroll
        for (int e = 0; e < DZ_; ++e) acc[e] = fmaf(wA, zAv[e], acc[e]);
        #pragma unroll
        for (int e = 0; e < DZ_; ++e) acc[e] = fmaf(wB, zBv[e], acc[e]);

        // rotate pipeline registers (unroll-2 ping-pongs these away)
        pA = pA2; pB = pB2; nA = nA2; nB = nB2;
        #pragma unroll
        for (int e = 0; e < DZ_; ++e) { zAv[e] = zA2v[e]; zBv[e] = zB2v[e]; }
    }

    __syncthreads();   // cuc/cidx reads done before red overlays them

    // ---- phase 3: block reduce (stride-17 = conflict-free), atomic store ----
    #pragma unroll
    for (int e = 0; e < DZ_; ++e) sm.red[w][j][e] = acc[e];
    __syncthreads();

    const int jj = tid >> 2;               // 0..63
    const int eg = (tid & 3) * 4;          // 0,4,8,12
    float4 s4 = make_float4(0.f, 0.f, 0.f, 0.f);
    #pragma unroll
    for (int ww = 0; ww < 4; ++ww) {
        s4.x += sm.red[ww][jj][eg + 0];
        s4.y += sm.red[ww][jj][eg + 1];
        s4.z += sm.red[ww][jj][eg + 2];
        s4.w += sm.red[ww][jj][eg + 3];
    }
    float* o = out + XGRID_SIZE
             + ((size_t)(((b*NT_ + t)*H_ + i)*W_ + jj))*DZ_ + eg;
    atomicAdd(o + 0, s4.x);
    atomicAdd(o + 1, s4.y);
    atomicAdd(o + 2, s4.z);
    atomicAdd(o + 3, s4.w);
}

extern "C" void kernel_launch(void* const* d_in, const int* in_sizes, int n_in,
                              void* d_out, int out_size, void* d_ws, size_t ws_size,
                              hipStream_t stream) {
    const float* x   = (const float*)d_in[0];   // [B][N][3]
    const float* z   = (const float*)d_in[1];   // [B][N][16]
    const float* tg  = (const float*)d_in[2];   // [B][NT]
    const float* lsp = (const float*)d_in[3];   // [3]

    float* out = (float*)d_out;

    // zero z_grid (atomic accumulation target); graph-capturable async memset
    hipMemsetAsync((void*)(out + XGRID_SIZE), 0,
                   (size_t)ZGRID_SIZE * sizeof(float), stream);

    // 4 n-splits * 1024 rows = 4096 blocks (16 queued per CU); no workspace.
    fused_kernel<<<NSPLIT*1024, 256, 0, stream>>>(x, z, tg, lsp, out);
}

// Round 6
// 100.899 us; speedup vs baseline: 1.1723x; 1.1723x over previous
//
#include <hip/hip_runtime.h>
#include <math.h>

#define B_  2
#define N_  2048
#define NT_ 8
#define DZ_ 16
#define H_  64
#define W_  64

#define NSPLIT 2
#define NCH (N_/NSPLIT)               // 1024 n's per block
#define CH  128                       // staged chunk size (compacted entries)

#define XGRID_SIZE (B_*NT_*H_*W_*3)   // 196608 floats
#define ZGRID_SIZE (B_*NT_*H_*W_*DZ_) // 1048576 floats
#define CUT 16.0f                     // exp2(-16) ~ 1.5e-5; dropped mass ~5e-4

// ---------------------------------------------------------------------------
// R6: no VMEM in the inner loop. Chunked double-buffered LDS staging of the
// compacted z rows; inner loop = pure VALU + broadcast LDS reads.
//
// R5 lesson (reverted): s_load z-prefetch is structurally unpipelineable —
// SMEM shares lgkmcnt with DS and returns out-of-order, so every in-loop
// ds_read forces lgkmcnt(0), draining the scalar prefetch. Also NSPLIT=4
// doubled atomic WRITE_SIZE; back to 2.
//
// Block = (split s, b, t, i): n in [s*1024, s*1024+1024) for one (b,t,i) row.
// phase 1: cull (dt*r0)^2+(di*r1)^2 < CUT, ballot-compact {exp2(-s), cx, n}
//          into LDS; pad 128 zero-weight entries (guard-free everything).
// phase 2: for each 128-entry chunk: cooperative gather of z rows
//          (2 float4/thread) -> ds_write_b128 -> 1 barrier -> issue next
//          chunk's loads (land during compute) -> wave w computes entries
//          m = w+4q from LDS (broadcast reads, conflict-free).
// phase 3: stride-17 LDS reduce (unions the z-stage), 4 f32 atomics/thread.
// ---------------------------------------------------------------------------
__global__ __launch_bounds__(256, 4) void fused_kernel(
    const float* __restrict__ x,      // [B][N][3]
    const float* __restrict__ z,      // [B][N][16]
    const float* __restrict__ tg,     // [B][NT]
    const float* __restrict__ lsp,    // [3]
    float* __restrict__ out)          // x_grid (196608) ++ z_grid (1048576)
{
    const int rest = blockIdx.x & 1023;
    const int s    = blockIdx.x >> 10;   // n-split id 0..1
    const int i    = rest & 63;
    const int t    = (rest >> 6) & 7;
    const int b    = rest >> 9;
    const int tid  = threadIdx.x;
    const int w    = tid >> 6;     // wave id 0..3
    const int lane = tid & 63;
    const int j    = lane;         // lane = spatial j

    const float step = 2.0f / 63.0f;
    const float C    = 0.84932180f;   // sqrt(0.5 * log2(e))

    const float r0 = C / (1e-5f + log1pf(expf(lsp[0])));
    const float r1 = C / (1e-5f + log1pf(expf(lsp[1])));
    const float r2 = C / (1e-5f + log1pf(expf(lsp[2])));

    const float tval = tg[b*NT_ + t];
    const float gi   = -1.0f + step * (float)i;

    struct SM {
        float2 cuc[NCH + CH];          // 9216 B
        int    cidx[NCH + CH];         // 4608 B
        union {
            float zs[2][CH * DZ_];     // 16384 B (ping-pong z stage)
            float red[4][64][DZ_ + 1]; // 17408 B (phase-3 reduce)
        } u;
    };                                  // 31232 B -> 5 blocks/CU
    __shared__ SM sm;
    __shared__ int s_cnt;

    if (tid == 0) s_cnt = 0;
    __syncthreads();

    // ---- phase 1: cull + compact this split's n-chunk ----
    const int nbase = s * NCH;
    const float* __restrict__ xb = x + (b*N_ + nbase)*3;
    for (int k0 = 0; k0 < NCH; k0 += 256) {
        int k = k0 + tid;
        float x0 = xb[k*3 + 0];
        float x1 = xb[k*3 + 1];
        float x2 = xb[k*3 + 2];
        float dt = (tval - x0) * r0;
        float di = (gi   - x1) * r1;
        float sq = dt*dt + di*di;
        bool keep = (sq < CUT);
        unsigned long long mb = __ballot(keep);
        int cnt = __popcll(mb);
        int base = 0;
        if (lane == 0) base = atomicAdd(&s_cnt, cnt);
        base = __shfl(base, 0, 64);
        if (keep) {
            int rank = __popcll(mb & ((1ull << lane) - 1ull));
            int pos  = base + rank;
            sm.cuc[pos]  = make_float2(exp2f(-sq), x2 * r2);
            sm.cidx[pos] = nbase + k;
        }
    }

    // x_grid row for this (b,t,i): written once (split 0 only), coalesced
    if (s == 0 && tid < 192) {
        int jj = tid / 3;
        int c  = tid - jj*3;
        float gj = -1.0f + step * (float)jj;
        float v  = (c == 0) ? tval : ((c == 1) ? gi : gj);
        out[(size_t)(((b*NT_ + t)*H_ + i)*W_)*3 + tid] = v;
    }

    __syncthreads();
    const int M = s_cnt;
    if (tid < CH) {                    // zero-weight padding to chunk multiple
        sm.cuc[M + tid]  = make_float2(0.f, 0.f);
        sm.cidx[M + tid] = 0;
    }
    __syncthreads();

    // ---- phase 2: chunked LDS-staged accumulate ----
    const float aj = (-1.0f + step * (float)j) * r2;
    const float* __restrict__ zb = z + b*N_*DZ_;

    float acc[DZ_];
    #pragma unroll
    for (int e = 0; e < DZ_; ++e) acc[e] = 0.0f;

    const int nchunks = (M + CH - 1) >> 7;
    const int r0i = tid >> 2;             // row handled by load 0 (0..63)
    const int r1i = (tid + 256) >> 2;     // row handled by load 1 (64..127)
    const int pi  = (tid & 3) * 4;        // float offset within row

    float4 st0, st1;
    if (nchunks > 0) {                    // prologue: gather chunk 0
        int n0 = sm.cidx[r0i];
        int n1 = sm.cidx[r1i];
        st0 = *(const float4*)(zb + (size_t)n0 * DZ_ + pi);
        st1 = *(const float4*)(zb + (size_t)n1 * DZ_ + pi);
    }

    for (int c = 0; c < nchunks; ++c) {
        const int buf = c & 1;
        float4* zs4 = (float4*)sm.u.zs[buf];
        zs4[tid]       = st0;             // ds_write_b128, linear, full-BW
        zs4[tid + 256] = st1;
        __syncthreads();                  // chunk c staged (all waves)

        if (c + 1 < nchunks) {            // issue gathers for chunk c+1 now;
            int cb = (c + 1) << 7;        // they land during compute below
            int n0 = sm.cidx[cb + r0i];
            int n1 = sm.cidx[cb + r1i];
            st0 = *(const float4*)(zb + (size_t)n0 * DZ_ + pi);
            st1 = *(const float4*)(zb + (size_t)n1 * DZ_ + pi);
        }

        const float2* __restrict__ cucc = sm.cuc + (c << 7);
        const float4* __restrict__ zsb  = (const float4*)sm.u.zs[buf];
        #pragma unroll 4
        for (int m = w; m < CH; m += 4) { // 32 entries per wave per chunk
            float2 p  = cucc[m];          // ds_read_b64 broadcast
            float d   = aj - p.y;
            float wgt = p.x * exp2f(-(d*d));
            float4 z0 = zsb[m*4 + 0];     // ds_read_b128 broadcast x4
            float4 z1 = zsb[m*4 + 1];
            float4 z2 = zsb[m*4 + 2];
            float4 z3 = zsb[m*4 + 3];
            acc[ 0] = fmaf(wgt, z0.x, acc[ 0]);
            acc[ 1] = fmaf(wgt, z0.y, acc[ 1]);
            acc[ 2] = fmaf(wgt, z0.z, acc[ 2]);
            acc[ 3] = fmaf(wgt, z0.w, acc[ 3]);
            acc[ 4] = fmaf(wgt, z1.x, acc[ 4]);
            acc[ 5] = fmaf(wgt, z1.y, acc[ 5]);
            acc[ 6] = fmaf(wgt, z1.z, acc[ 6]);
            acc[ 7] = fmaf(wgt, z1.w, acc[ 7]);
            acc[ 8] = fmaf(wgt, z2.x, acc[ 8]);
            acc[ 9] = fmaf(wgt, z2.y, acc[ 9]);
            acc[10] = fmaf(wgt, z2.z, acc[10]);
            acc[11] = fmaf(wgt, z2.w, acc[11]);
            acc[12] = fmaf(wgt, z3.x, acc[12]);
            acc[13] = fmaf(wgt, z3.y, acc[13]);
            acc[14] = fmaf(wgt, z3.z, acc[14]);
            acc[15] = fmaf(wgt, z3.w, acc[15]);
        }
    }

    __syncthreads();   // all reads of zs done before red overlays it

    // ---- phase 3: block reduce (stride-17 = conflict-free), atomic store ----
    #pragma unroll
    for (int e = 0; e < DZ_; ++e) sm.u.red[w][j][e] = acc[e];
    __syncthreads();

    const int jj = tid >> 2;               // 0..63
    const int eg = (tid & 3) * 4;          // 0,4,8,12
    float4 s4 = make_float4(0.f, 0.f, 0.f, 0.f);
    #pragma unroll
    for (int ww = 0; ww < 4; ++ww) {
        s4.x += sm.u.red[ww][jj][eg + 0];
        s4.y += sm.u.red[ww][jj][eg + 1];
        s4.z += sm.u.red[ww][jj][eg + 2];
        s4.w += sm.u.red[ww][jj][eg + 3];
    }
    float* o = out + XGRID_SIZE
             + ((size_t)(((b*NT_ + t)*H_ + i)*W_ + jj))*DZ_ + eg;
    atomicAdd(o + 0, s4.x);
    atomicAdd(o + 1, s4.y);
    atomicAdd(o + 2, s4.z);
    atomicAdd(o + 3, s4.w);
}

extern "C" void kernel_launch(void* const* d_in, const int* in_sizes, int n_in,
                              void* d_out, int out_size, void* d_ws, size_t ws_size,
                              hipStream_t stream) {
    const float* x   = (const float*)d_in[0];   // [B][N][3]
    const float* z   = (const float*)d_in[1];   // [B][N][16]
    const float* tg  = (const float*)d_in[2];   // [B][NT]
    const float* lsp = (const float*)d_in[3];   // [3]

    float* out = (float*)d_out;

    // zero z_grid (atomic accumulation target); graph-capturable async memset
    hipMemsetAsync((void*)(out + XGRID_SIZE), 0,
                   (size_t)ZGRID_SIZE * sizeof(float), stream);

    // 2 n-splits * 1024 rows = 2048 blocks; no workspace used.
    fused_kernel<<<NSPLIT*1024, 256, 0, stream>>>(x, z, tg, lsp, out);
}

// Round 7
// 75.802 us; speedup vs baseline: 1.5604x; 1.3311x over previous
//
#include <hip/hip_runtime.h>
#include <math.h>

#define B_  2
#define N_  2048
#define NT_ 8
#define DZ_ 16
#define H_  64
#define W_  64

#define XGRID_SIZE (B_*NT_*H_*W_*3)   // 196608 floats
#define CUT 16.0f                     // keep if dt^2+di^2 < 16 (w > 1.5e-5)
#define CH  64                        // K-chunk: 2 MFMAs of K=32
#define RSH 72                        // zT row stride in f16 (144 B: 16B-aligned, odd dword stride)

using half8   = __attribute__((ext_vector_type(8))) _Float16;
using half2v  = __attribute__((ext_vector_type(2))) _Float16;
using floatx4 = __attribute__((ext_vector_type(4))) float;

// ---------------------------------------------------------------------------
// R7: MFMA path. R6 was LDS-return-BW bound (54 cy/entry of broadcast reads,
// 63/64 of LDS bandwidth wasted). MFMA B-fragments distribute z across lanes
// (16 B/lane per 32 entries instead of 2 KB/lane) -> ~7x less LDS traffic;
// FMAs move to the matrix pipe (f16 in, f32 acc).
//
// Block = one (b,t,i) row. Wave w computes output tile j in [w*16, w*16+16),
// e in [0,16) as one 16x16 MFMA accumulator. K = compacted entries.
// phase 1: cull dt^2+di^2 < CUT, ballot-compact meta {s = dt^2+di^2, cx}
//          (no exp here: weight = exp2(-(d^2 + s)) later, one exp/element).
// phase 2: per 64-entry chunk: (a) write previously-loaded z regs -> zT[buf]
//          as f16 [e][k] (transposed, row stride 72 f16); (b) barrier;
//          (c) issue next chunk's global z loads (land during compute);
//          (d) per wave: meta -> 16 weights/lane -> 2x A-frag (half8),
//          B-frag = 1x ds_read_b128 per half, 2x mfma_f32_16x16x32_f16.
// epilogue: D layout col=lane&15,row=quad*4+reg -> 4 coalesced dword stores.
// No atomics, no memset, no workspace.
// ---------------------------------------------------------------------------
__global__ __launch_bounds__(256, 4) void fused_kernel(
    const float* __restrict__ x,      // [B][N][3]
    const float* __restrict__ z,      // [B][N][16]
    const float* __restrict__ tg,     // [B][NT]
    const float* __restrict__ lsp,    // [3]
    float* __restrict__ out)          // x_grid (196608) ++ z_grid (1048576)
{
    const int i    = blockIdx.x & 63;
    const int t    = (blockIdx.x >> 6) & 7;
    const int b    = blockIdx.x >> 9;
    const int tid  = threadIdx.x;
    const int w    = tid >> 6;        // wave id = j-tile
    const int lane = tid & 63;
    const int quad = lane >> 4;       // 0..3
    const int col  = lane & 15;       // MFMA col (e) / A row (m)

    const float step = 2.0f / 63.0f;
    const float C    = 0.84932180f;   // sqrt(0.5 * log2(e))

    const float r0 = C / (1e-5f + log1pf(expf(lsp[0])));
    const float r1 = C / (1e-5f + log1pf(expf(lsp[1])));
    const float r2 = C / (1e-5f + log1pf(expf(lsp[2])));

    const float tval = tg[b*NT_ + t];
    const float gi   = -1.0f + step * (float)i;

    __shared__ float2    cuc[N_ + CH];        // {s, cx}: 16896 B
    __shared__ int       cidx[N_ + CH];       // 8448 B
    __shared__ _Float16  zT[2][16 * RSH];     // 4608 B  [buf][e*RSH + k]
    __shared__ int s_cnt;

    if (tid == 0) s_cnt = 0;
    __syncthreads();

    // ---- phase 1: cull + compact (s, cx) over all n ----
    const float* __restrict__ xb = x + b*N_*3;
    for (int k0 = 0; k0 < N_; k0 += 256) {
        int k = k0 + tid;
        float x0 = xb[k*3 + 0];
        float x1 = xb[k*3 + 1];
        float x2 = xb[k*3 + 2];
        float dt = (tval - x0) * r0;
        float di = (gi   - x1) * r1;
        float sq = fmaf(dt, dt, di*di);
        bool keep = (sq < CUT);
        unsigned long long mb = __ballot(keep);
        int cnt = __popcll(mb);
        int base = 0;
        if (lane == 0) base = atomicAdd(&s_cnt, cnt);
        base = __shfl(base, 0, 64);
        if (keep) {
            int rank = __popcll(mb & ((1ull << lane) - 1ull));
            int pos  = base + rank;
            cuc[pos]  = make_float2(sq, x2 * r2);
            cidx[pos] = k;
        }
    }

    // x_grid row for this (b,t,i): 192 floats, coalesced
    if (tid < 192) {
        int jj = tid / 3;
        int c  = tid - jj*3;
        float gj = -1.0f + step * (float)jj;
        float v  = (c == 0) ? tval : ((c == 1) ? gi : gj);
        out[(size_t)blockIdx.x * 192 + tid] = v;
    }

    __syncthreads();
    const int M = s_cnt;
    if (tid < CH) {                    // pad: s huge -> exp2(-(d^2+s)) == 0
        cuc[M + tid]  = make_float2(1e9f, 0.f);
        cidx[M + tid] = 0;
    }
    __syncthreads();

    const int NC = (M + CH - 1) / CH;  // 64-entry chunks (>=0)

    // ---- phase 2: double-buffered staged MFMA K-loop ----
    const float* __restrict__ zb = z + b*N_*DZ_;
    const float ajm = (-1.0f + step * (float)(w*16 + col)) * r2;  // A-row coord

    // staging mapping: thread -> (e = tid&15, k = 4*(tid>>4) .. +3)
    const int se = tid & 15;
    const int ks = (tid >> 4) * 4;

    floatx4 acc = {0.f, 0.f, 0.f, 0.f};
    float rg0, rg1, rg2, rg3;

    if (NC > 0) {                      // prologue: load chunk 0 z values
        rg0 = zb[(size_t)cidx[ks + 0] * DZ_ + se];
        rg1 = zb[(size_t)cidx[ks + 1] * DZ_ + se];
        rg2 = zb[(size_t)cidx[ks + 2] * DZ_ + se];
        rg3 = zb[(size_t)cidx[ks + 3] * DZ_ + se];
    }

    for (int c = 0; c < NC; ++c) {
        const int buf = c & 1;

        // (a) stage chunk c into zT[buf] (f16, transposed [e][k])
        half2v h01 = { (_Float16)rg0, (_Float16)rg1 };
        half2v h23 = { (_Float16)rg2, (_Float16)rg3 };
        *(half2v*)&zT[buf][se*RSH + ks]     = h01;
        *(half2v*)&zT[buf][se*RSH + ks + 2] = h23;
        __syncthreads();

        // (b) issue global loads for chunk c+1 (consumed next iteration)
        if (c + 1 < NC) {
            const int base2 = (c + 1) * CH;
            rg0 = zb[(size_t)cidx[base2 + ks + 0] * DZ_ + se];
            rg1 = zb[(size_t)cidx[base2 + ks + 1] * DZ_ + se];
            rg2 = zb[(size_t)cidx[base2 + ks + 2] * DZ_ + se];
            rg3 = zb[(size_t)cidx[base2 + ks + 3] * DZ_ + se];
        }

        // (c) compute chunk c: weights -> A-frags, zT -> B-frags, 2 MFMAs
        const int base = c * CH;
        const float2* __restrict__ mp0 = &cuc[base + quad*8];        // k 0..31 part
        const float2* __restrict__ mp1 = &cuc[base + 32 + quad*8];   // k 32..63 part

        half8 a0, a1;
        #pragma unroll
        for (int jj = 0; jj < 8; ++jj) {
            float2 mm = mp0[jj];
            float d = ajm - mm.y;
            a0[jj] = (_Float16)exp2f(-fmaf(d, d, mm.x));
        }
        #pragma unroll
        for (int jj = 0; jj < 8; ++jj) {
            float2 mm = mp1[jj];
            float d = ajm - mm.y;
            a1[jj] = (_Float16)exp2f(-fmaf(d, d, mm.x));
        }

        half8 b0 = *(const half8*)&zT[buf][col*RSH + quad*8];
        half8 b1 = *(const half8*)&zT[buf][col*RSH + 32 + quad*8];

        acc = __builtin_amdgcn_mfma_f32_16x16x32_f16(a0, b0, acc, 0, 0, 0);
        acc = __builtin_amdgcn_mfma_f32_16x16x32_f16(a1, b1, acc, 0, 0, 0);
    }

    // ---- epilogue: D (col=lane&15, row=quad*4+reg) -> z_grid ----
    float* og = out + XGRID_SIZE + (size_t)blockIdx.x * (W_ * DZ_);
    #pragma unroll
    for (int reg = 0; reg < 4; ++reg) {
        int j = w*16 + quad*4 + reg;
        og[j*DZ_ + col] = acc[reg];
    }
}

extern "C" void kernel_launch(void* const* d_in, const int* in_sizes, int n_in,
                              void* d_out, int out_size, void* d_ws, size_t ws_size,
                              hipStream_t stream) {
    const float* x   = (const float*)d_in[0];   // [B][N][3]
    const float* z   = (const float*)d_in[1];   // [B][N][16]
    const float* tg  = (const float*)d_in[2];   // [B][NT]
    const float* lsp = (const float*)d_in[3];   // [3]

    float* out = (float*)d_out;

    // 1024 blocks, one per (b,t,i) row; no workspace, no memset, no atomics.
    fused_kernel<<<1024, 256, 0, stream>>>(x, z, tg, lsp, out);
}

// Round 8
// 72.757 us; speedup vs baseline: 1.6257x; 1.0419x over previous
//
#include <hip/hip_runtime.h>
#include <math.h>

#define B_  2
#define N_  2048
#define NT_ 8
#define DZ_ 16
#define H_  64
#define W_  64

#define XGRID_SIZE (B_*NT_*H_*W_*3)   // 196608 floats
#define CUT 12.0f                     // keep if dt^2+di^2 < 12 (w > 2.4e-4)
#define CH  128                       // K-chunk: 4 waves x K=32

using half8   = __attribute__((ext_vector_type(8))) _Float16;
using floatx4 = __attribute__((ext_vector_type(4))) float;

// ---------------------------------------------------------------------------
// R8: barrier-free MFMA K-loop with k-split waves.
//
// R7 model: per-chunk staging barrier + 4x-redundant broadcast meta reads
// made the K-loop LDS/barrier-bound (~27K cy/CU). Fix: wave w owns
// k-subrange [w*32, w*32+32) of each 128-entry chunk and computes ALL FOUR
// 16x16 j-tiles from it: one B-frag (loaded DIRECTLY from global z — 64 B
// coalesced per quad, L2-resident) reused by 4 MFMAs with per-tile A-frags.
// Meta reads: each wave reads only its own 8 entries/quad (no redundancy).
// NO __syncthreads in the K-loop at all; 1-chunk-deep B prefetch.
// End: one LDS tree-reduce of the 4 k-partials (stride-17, conflict-light),
// plain coalesced float4 stores. No atomics, no memset, no workspace.
//
// MFMA f16 16x16x32 layouts (verified m89/m91/m120):
//   A[m=lane&15][k=quad*8+jj], B[k=quad*8+jj][n=lane&15],
//   D: col=lane&15, row=quad*4+reg.
// Here m = j within tile, n = e, k = compacted entry.
// ---------------------------------------------------------------------------
__global__ __launch_bounds__(256, 4) void fused_kernel(
    const float* __restrict__ x,      // [B][N][3]
    const float* __restrict__ z,      // [B][N][16]
    const float* __restrict__ tg,     // [B][NT]
    const float* __restrict__ lsp,    // [3]
    float* __restrict__ out)          // x_grid (196608) ++ z_grid (1048576)
{
    const int i    = blockIdx.x & 63;
    const int t    = (blockIdx.x >> 6) & 7;
    const int b    = blockIdx.x >> 9;
    const int tid  = threadIdx.x;
    const int w    = tid >> 6;        // wave id = k-subrange
    const int lane = tid & 63;
    const int quad = lane >> 4;       // 0..3
    const int col  = lane & 15;       // A row (j in tile) / B col (e)

    const float step = 2.0f / 63.0f;
    const float C    = 0.84932180f;   // sqrt(0.5 * log2(e))

    const float r0 = C / (1e-5f + log1pf(expf(lsp[0])));
    const float r1 = C / (1e-5f + log1pf(expf(lsp[1])));
    const float r2 = C / (1e-5f + log1pf(expf(lsp[2])));

    const float tval = tg[b*NT_ + t];
    const float gi   = -1.0f + step * (float)i;

    union REDU {
        float2 cuc[N_ + CH];           // {s, cx}: 17408 B (phases 1-2)
        float  red[4][64][DZ_ + 1];    // 17408 B (epilogue reduce)
    };
    __shared__ REDU sm;
    __shared__ int  cidx[N_ + CH];     // 8704 B
    __shared__ int  s_cnt;

    if (tid == 0) s_cnt = 0;
    __syncthreads();

    // ---- phase 1: cull + compact (s = dt^2+di^2, cx) over all n ----
    const float* __restrict__ xb = x + b*N_*3;
    for (int k0 = 0; k0 < N_; k0 += 256) {
        int k = k0 + tid;
        float x0 = xb[k*3 + 0];
        float x1 = xb[k*3 + 1];
        float x2 = xb[k*3 + 2];
        float dt = (tval - x0) * r0;
        float di = (gi   - x1) * r1;
        float sq = fmaf(dt, dt, di*di);
        bool keep = (sq < CUT);
        unsigned long long mb = __ballot(keep);
        int cnt = __popcll(mb);
        int base = 0;
        if (lane == 0) base = atomicAdd(&s_cnt, cnt);
        base = __shfl(base, 0, 64);
        if (keep) {
            int rank = __popcll(mb & ((1ull << lane) - 1ull));
            int pos  = base + rank;
            sm.cuc[pos] = make_float2(sq, x2 * r2);
            cidx[pos]   = k;
        }
    }

    // x_grid row for this (b,t,i): 192 floats, coalesced
    if (tid < 192) {
        int jj = tid / 3;
        int c  = tid - jj*3;
        float gj = -1.0f + step * (float)jj;
        float v  = (c == 0) ? tval : ((c == 1) ? gi : gj);
        out[(size_t)blockIdx.x * 192 + tid] = v;
    }

    __syncthreads();
    const int M = s_cnt;
    if (tid < CH) {                    // pad: s huge -> exp2(-(d^2+s)) == 0
        sm.cuc[M + tid] = make_float2(1e9f, 0.f);
        cidx[M + tid]   = 0;
    }
    __syncthreads();

    const int NC = (M + CH - 1) / CH;  // 128-entry chunks

    // ---- phase 2: barrier-free MFMA K-loop ----
    const float* __restrict__ zb = z + b*N_*DZ_;
    const int koff = w*32 + (quad << 3);   // this lane's k-base within a chunk

    const float aj0 = (-1.0f + step * (float)( 0 + col)) * r2;
    const float aj1 = (-1.0f + step * (float)(16 + col)) * r2;
    const float aj2 = (-1.0f + step * (float)(32 + col)) * r2;
    const float aj3 = (-1.0f + step * (float)(48 + col)) * r2;

    floatx4 acc0 = {0.f,0.f,0.f,0.f};
    floatx4 acc1 = {0.f,0.f,0.f,0.f};
    floatx4 acc2 = {0.f,0.f,0.f,0.f};
    floatx4 acc3 = {0.f,0.f,0.f,0.f};

    // prologue: B dwords for chunk 0 (pads make indices always valid)
    float zreg[8];
    {
        int idx[8];
        #pragma unroll
        for (int jj = 0; jj < 8; ++jj) idx[jj] = cidx[koff + jj];
        #pragma unroll
        for (int jj = 0; jj < 8; ++jj)
            zreg[jj] = zb[(size_t)idx[jj] * DZ_ + col];
    }

    for (int c = 0; c < NC; ++c) {
        // pack current B fragment
        half8 bf;
        #pragma unroll
        for (int jj = 0; jj < 8; ++jj) bf[jj] = (_Float16)zreg[jj];

        // meta for current chunk (quad-uniform broadcast, 8 entries/lane)
        const int base = c*CH + koff;
        float2 mm[8];
        #pragma unroll
        for (int jj = 0; jj < 8; ++jj) mm[jj] = sm.cuc[base + jj];

        // prefetch next chunk's B dwords (land during exp/MFMA below)
        if (c + 1 < NC) {
            const int base2 = (c + 1)*CH + koff;
            int idx[8];
            #pragma unroll
            for (int jj = 0; jj < 8; ++jj) idx[jj] = cidx[base2 + jj];
            #pragma unroll
            for (int jj = 0; jj < 8; ++jj)
                zreg[jj] = zb[(size_t)idx[jj] * DZ_ + col];
        }

        // A fragments for the 4 j-tiles
        half8 a0, a1, a2, a3;
        #pragma unroll
        for (int jj = 0; jj < 8; ++jj) {
            float s  = mm[jj].x;
            float cx = mm[jj].y;
            float d0 = aj0 - cx;
            float d1 = aj1 - cx;
            float d2 = aj2 - cx;
            float d3 = aj3 - cx;
            a0[jj] = (_Float16)exp2f(-fmaf(d0, d0, s));
            a1[jj] = (_Float16)exp2f(-fmaf(d1, d1, s));
            a2[jj] = (_Float16)exp2f(-fmaf(d2, d2, s));
            a3[jj] = (_Float16)exp2f(-fmaf(d3, d3, s));
        }

        acc0 = __builtin_amdgcn_mfma_f32_16x16x32_f16(a0, bf, acc0, 0, 0, 0);
        acc1 = __builtin_amdgcn_mfma_f32_16x16x32_f16(a1, bf, acc1, 0, 0, 0);
        acc2 = __builtin_amdgcn_mfma_f32_16x16x32_f16(a2, bf, acc2, 0, 0, 0);
        acc3 = __builtin_amdgcn_mfma_f32_16x16x32_f16(a3, bf, acc3, 0, 0, 0);
    }

    __syncthreads();   // all cuc reads done before red overlays it

    // ---- epilogue: reduce 4 k-partials across waves, store z_grid ----
    // D layout: row = quad*4 + reg, col = lane&15.
    #pragma unroll
    for (int r = 0; r < 4; ++r) sm.red[w][ 0 + quad*4 + r][col] = acc0[r];
    #pragma unroll
    for (int r = 0; r < 4; ++r) sm.red[w][16 + quad*4 + r][col] = acc1[r];
    #pragma unroll
    for (int r = 0; r < 4; ++r) sm.red[w][32 + quad*4 + r][col] = acc2[r];
    #pragma unroll
    for (int r = 0; r < 4; ++r) sm.red[w][48 + quad*4 + r][col] = acc3[r];
    __syncthreads();

    const int jj = tid >> 2;               // 0..63
    const int eg = (tid & 3) * 4;          // 0,4,8,12
    float4 s4 = make_float4(0.f, 0.f, 0.f, 0.f);
    #pragma unroll
    for (int ww = 0; ww < 4; ++ww) {
        s4.x += sm.red[ww][jj][eg + 0];
        s4.y += sm.red[ww][jj][eg + 1];
        s4.z += sm.red[ww][jj][eg + 2];
        s4.w += sm.red[ww][jj][eg + 3];
    }
    float* og = out + XGRID_SIZE + (size_t)blockIdx.x * (W_ * DZ_);
    *(float4*)(og + jj*DZ_ + eg) = s4;
}

extern "C" void kernel_launch(void* const* d_in, const int* in_sizes, int n_in,
                              void* d_out, int out_size, void* d_ws, size_t ws_size,
                              hipStream_t stream) {
    const float* x   = (const float*)d_in[0];   // [B][N][3]
    const float* z   = (const float*)d_in[1];   // [B][N][16]
    const float* tg  = (const float*)d_in[2];   // [B][NT]
    const float* lsp = (const float*)d_in[3];   // [3]

    float* out = (float*)d_out;

    // 1024 blocks, one per (b,t,i) row; no workspace, no memset, no atomics.
    fused_kernel<<<1024, 256, 0, stream>>>(x, z, tg, lsp, out);
}